// Round 3
// baseline (5930.465 us; speedup 1.0000x reference)
//
#include <hip/hip_runtime.h>
#include <hip/hip_fp16.h>
#include <cstddef>
#include <cstdint>

#define B_  256
#define T_  512
#define D_  128
#define H_  256
#define G3_ 768
#define C_  10

typedef _Float16 f16x8 __attribute__((ext_vector_type(8)));
typedef float    f32x4 __attribute__((ext_vector_type(4)));

__device__ __forceinline__ float sigmoid_f(float x) {
    return 1.0f / (1.0f + __expf(-x));
}
__device__ __forceinline__ float tanh_f(float x) {
    return 1.0f - 2.0f / (__expf(2.0f * x) + 1.0f);
}

__device__ __forceinline__ unsigned int packh2(float a, float b) {
    unsigned short lo = __half_as_ushort(__float2half(a));   // k even -> lo16
    unsigned short hi = __half_as_ushort(__float2half(b));   // k odd  -> hi16
    return (unsigned int)lo | ((unsigned int)hi << 16);
}

// ---------------------------------------------------------------------------
// Pack Whh[3H][H] fp32 -> f16 MFMA B-fragment stream for the scan.
// Fragment (w, nt, kt): wave w owns gate-cols c0 = g*256 + w*32 + (nt&1)*16
// (g = nt>>1: 0=r, 1=z, 2=n), K-tile kt (32 wide).
// v_mfma_f32_16x16x32_f16 B layout: lane l supplies B[k][n] with
//   n = c0 + (l&15), k = kt*32 + (l>>4)*8 + i (i = 0..7, contiguous).
// Wl[((w*6+nt)*8+kt)*64 + l] = uint4 of those 8 f16.
// grid: 48 blocks x 512 threads. 393,216 B per layer.
// ---------------------------------------------------------------------------
__global__ void k_pack_whh(const float* __restrict__ Whh, uint4* __restrict__ Wl) {
    const int wnt = blockIdx.x;          // w*6 + nt
    const int w  = wnt / 6;
    const int nt = wnt % 6;
    const int t  = threadIdx.x;
    const int kt = t >> 6;
    const int l  = t & 63;
    const int g  = nt >> 1;
    const int n  = g * 256 + w * 32 + (nt & 1) * 16 + (l & 15);
    const int k0 = kt * 32 + (l >> 4) * 8;
    const float* row = Whh + (size_t)n * H_ + k0;
    uint4 u;
    u.x = packh2(row[0], row[1]);
    u.y = packh2(row[2], row[3]);
    u.z = packh2(row[4], row[5]);
    u.w = packh2(row[6], row[7]);
    Wl[(size_t)wnt * 512 + t] = u;
}

// ---------------------------------------------------------------------------
// C[M,N] = A[M,K] @ W[N,K]^T + bias[N]  (fp32 NT, chunk-major A rows).
// (unchanged -- next optimization target once the scan is fixed)
// ---------------------------------------------------------------------------
__global__ __launch_bounds__(256, 2) void k_gemm_nt_bias(
    const float* __restrict__ A, long Abstride,
    const float* __restrict__ W,
    const float* __restrict__ bias, float* __restrict__ C,
    int N, int K, int tcShift)
{
    __shared__ float As[16][128];
    __shared__ float Ws[16][64];
    const int tid = threadIdx.x;
    const int tx = tid & 15;
    const int ty = tid >> 4;
    const int m0 = blockIdx.y * 128;
    const int n0 = blockIdx.x * 64;
    const int arow = tid >> 1;
    const int ak   = (tid & 1) * 8;
    const int wrow = tid >> 2;
    const int wk   = (tid & 3) * 4;

    const int mask = (1 << tcShift) - 1;
    const int mg = m0 + arow;
    const float* Arow = A + (size_t)(mg >> tcShift) * Abstride + (size_t)(mg & mask) * K;
    const float* Wrow = W + (size_t)(n0 + wrow) * K;

    float acc[8][4] = {};

    for (int k0 = 0; k0 < K; k0 += 16) {
        float4 a0 = *(const float4*)&Arow[k0 + ak];
        float4 a1 = *(const float4*)&Arow[k0 + ak + 4];
        float4 wv = *(const float4*)&Wrow[k0 + wk];
        __syncthreads();
        As[ak + 0][arow] = a0.x; As[ak + 1][arow] = a0.y;
        As[ak + 2][arow] = a0.z; As[ak + 3][arow] = a0.w;
        As[ak + 4][arow] = a1.x; As[ak + 5][arow] = a1.y;
        As[ak + 6][arow] = a1.z; As[ak + 7][arow] = a1.w;
        Ws[wk + 0][wrow] = wv.x; Ws[wk + 1][wrow] = wv.y;
        Ws[wk + 2][wrow] = wv.z; Ws[wk + 3][wrow] = wv.w;
        __syncthreads();
#pragma unroll
        for (int kk = 0; kk < 16; kk++) {
            float a8[8], b4[4];
            *(float4*)&a8[0] = *(const float4*)&As[kk][ty * 8];
            *(float4*)&a8[4] = *(const float4*)&As[kk][ty * 8 + 4];
            *(float4*)&b4[0] = *(const float4*)&Ws[kk][tx * 4];
#pragma unroll
            for (int ii = 0; ii < 8; ii++)
#pragma unroll
                for (int jj = 0; jj < 4; jj++)
                    acc[ii][jj] = fmaf(a8[ii], b4[jj], acc[ii][jj]);
        }
    }

    float b4[4];
#pragma unroll
    for (int jj = 0; jj < 4; jj++) b4[jj] = bias[n0 + tx * 4 + jj];
#pragma unroll
    for (int ii = 0; ii < 8; ii++) {
        float4 v;
        v.x = acc[ii][0] + b4[0];
        v.y = acc[ii][1] + b4[1];
        v.z = acc[ii][2] + b4[2];
        v.w = acc[ii][3] + b4[3];
        *(float4*)&C[(size_t)(m0 + ty * 8 + ii) * N + n0 + tx * 4] = v;
    }
}

// ---------------------------------------------------------------------------
// MFMA scan. Block = 16 batch rows, 512 thr (8 waves), 1 block/CU (148 KB LDS).
// Per step: gates[16x768] = h[16x256] @ Whh^T via 48 v_mfma_f32_16x16x32_f16
// per wave (6 N-tiles x 8 K-tiles).
// Weights are CU-RESIDENT: nt 0..3 (r,z gates) = 32 frags pinned in 128 AGPRs;
// nt 4..5 (n gate) = 16 frags/wave in LDS (128 KB). No per-step L2 stream.
//
// R1 post-mortem: VGPR=124, compiler rematerialized the 32 weight loads
// in-loop (per-step L2 stream). R2 post-mortem: "+v" launder forced the
// values into ARCH VGPRs at the asm point; with the arch file pressured the
// allocator homed the chained values in AGPRs and SHUTTLED via
// v_accvgpr_read/write every step (VGPR stayed 128, VALUBusy ~59% on active
// CUs, time unchanged). Fix: launder with the "+a" (AGPR) constraint -- AGPR
// is the intended home, and gfx950 MFMA reads its B operand DIRECTLY from
// AGPRs (ISA §10, unified file), so residency costs zero per-step
// instructions. Budget: ~95 arch VGPR + 128 AGPR = 223 <= 256 @ 2 waves/SIMD.
//
// Also: per-step gi/out addresses are (uniform step base in SGPR, advanced
// by scalar add) + (lane offset precomputed once) + (13-bit imm offset) --
// removes all per-step 64-bit VALU address math.
// ---------------------------------------------------------------------------
__device__ __forceinline__ void gru_scan_core(
    const float* __restrict__ gi,      // + b0*Tc*G3   [16 rows][Tc][3H]
    const uint4* __restrict__ Wpk,     // [48*8][64] packed B-fragments
    const float* __restrict__ bhh,
    float* __restrict__ h_state,       // + b0*H
    float* __restrict__ out_seq,       // + b0*Tc*H or nullptr
    int Tc, int initZero,
    uint4 (&lds_w)[8192], _Float16 (&lds_h)[2][16][264])
{
    const int tid = threadIdx.x;
    const int w  = tid >> 6;       // wave 0..7
    const int l  = tid & 63;
    const int c  = l & 15;
    const int g4 = l >> 4;         // 0..3

    // ---- stage LDS-resident weight frags (nt 4,5 of every wave) -----------
#pragma unroll
    for (int i = 0; i < 16; i++) {
        int idx = i * 512 + tid;                       // (wv*16 + fl)*64 + ln
        lds_w[idx] = Wpk[(size_t)(idx >> 10) * 3072 + 2048 + (idx & 1023)];
    }

    // ---- AGPR-resident frags: nt 0..3 x kt 0..7 -> 128 AGPRs --------------
    f16x8 wreg[32];
#pragma unroll
    for (int nt = 0; nt < 4; nt++)
#pragma unroll
        for (int kt = 0; kt < 8; kt++)
            wreg[nt * 8 + kt] = *reinterpret_cast<const f16x8*>(
                Wpk + (size_t)((w * 6 + nt) * 8 + kt) * 64 + l);

    // ---- lane ownership: m = g4*4+r, j = w*32 + jj*16 + c -----------------
    const int jA = w * 32 + c;
    const float br0 = bhh[jA],       br1 = bhh[jA + 16];
    const float bz0 = bhh[256 + jA], bz1 = bhh[256 + jA + 16];
    const float bn0 = bhh[512 + jA], bn1 = bhh[512 + jA + 16];

    // step-invariant lane offsets (elements); step base advances uniformly
    int voff_gi[4], voff_os[4];
#pragma unroll
    for (int r = 0; r < 4; r++) {
        const int m = g4 * 4 + r;
        voff_gi[r] = m * Tc * G3_ + jA;
        voff_os[r] = m * Tc * H_  + jA;
    }

    float hreg[4][2];
#pragma unroll
    for (int r = 0; r < 4; r++) {
        const int m = g4 * 4 + r;
        if (initZero) {
            hreg[r][0] = 0.0f;
            hreg[r][1] = 0.0f;
        } else {
            hreg[r][0] = h_state[(size_t)m * H_ + jA];
            hreg[r][1] = h_state[(size_t)m * H_ + jA + 16];
        }
        lds_h[0][m][jA]      = (_Float16)hreg[r][0];
        lds_h[0][m][jA + 16] = (_Float16)hreg[r][1];
    }
    __syncthreads();

    const float* gi_step = gi;         // uniform: SGPR base, += G3_ per step
    float*       os_step = out_seq;    // uniform: SGPR base, += H_  per step

    int cur = 0;
    for (int tt = 0; tt < Tc; ++tt) {
        // ---- anti-remat: weight values opaque each step, pinned in AGPRs --
#pragma unroll
        for (int i = 0; i < 32; i++)
            asm volatile("" : "+a"(wreg[i]));

        // LICM barrier for the LDS-resident frags (offset opaque each step).
        unsigned wb = (unsigned)(w * 1024 + l);
        asm volatile("" : "+v"(wb));

        // gi prefetch: saddr + lane voffset + imm gate offsets (0..2112 B).
        float gic[4][6];
#pragma unroll
        for (int r = 0; r < 4; r++) {
            const float* gp = gi_step + voff_gi[r];
#pragma unroll
            for (int gg = 0; gg < 3; gg++) {
                gic[r][gg * 2 + 0] = gp[gg * 256];
                gic[r][gg * 2 + 1] = gp[gg * 256 + 16];
            }
        }

        f32x4 acc[6] = {};
#pragma unroll
        for (int kt = 0; kt < 8; kt++) {
            // A-frag: lane supplies h[c][kt*32 + g4*8 .. +8]  (ds_read_b128)
            f16x8 a = *(const f16x8*)&lds_h[cur][c][kt * 32 + g4 * 8];
#pragma unroll
            for (int nt = 0; nt < 4; nt++)
                acc[nt] = __builtin_amdgcn_mfma_f32_16x16x32_f16(
                    a, wreg[nt * 8 + kt], acc[nt], 0, 0, 0);
            uint4 u4 = lds_w[wb + kt * 64];            // nt=4 frag
            acc[4] = __builtin_amdgcn_mfma_f32_16x16x32_f16(
                a, __builtin_bit_cast(f16x8, u4), acc[4], 0, 0, 0);
            uint4 u5 = lds_w[wb + (8 + kt) * 64];      // nt=5 frag
            acc[5] = __builtin_amdgcn_mfma_f32_16x16x32_f16(
                a, __builtin_bit_cast(f16x8, u5), acc[5], 0, 0, 0);
        }

        // D layout (verified m89/m91): row m = g4*4 + reg, col = tile_c0 + c.
        // nt 0/1 = r-gate (jj=0/1), nt 2/3 = z, nt 4/5 = n.
#pragma unroll
        for (int r = 0; r < 4; r++) {
            const int m = g4 * 4 + r;
#pragma unroll
            for (int jj = 0; jj < 2; jj++) {
                float rg = sigmoid_f(gic[r][jj]     + acc[jj][r]     + (jj ? br1 : br0));
                float zg = sigmoid_f(gic[r][2 + jj] + acc[2 + jj][r] + (jj ? bz1 : bz0));
                float ng = tanh_f(gic[r][4 + jj] +
                                  rg * (acc[4 + jj][r] + (jj ? bn1 : bn0)));
                float hn = (1.0f - zg) * ng + zg * hreg[r][jj];
                hreg[r][jj] = hn;
                lds_h[cur ^ 1][m][jA + jj * 16] = (_Float16)hn;
                if (out_seq)
                    os_step[voff_os[r] + jj * 16] = hn;
            }
        }
        if (tt == Tc - 1) {
#pragma unroll
            for (int r = 0; r < 4; r++) {
                const int m = g4 * 4 + r;
                h_state[(size_t)m * H_ + jA]      = hreg[r][0];
                h_state[(size_t)m * H_ + jA + 16] = hreg[r][1];
            }
        }
        __syncthreads();
        cur ^= 1;
        gi_step += G3_;
        os_step += H_;
    }
}

// Fused layer-pipelined scan: blocks 0..15 -> layer0 chunk c (16 rows each),
// blocks 16..31 -> layer1 chunk c-1. 148 KB LDS -> 1 block/CU naturally.
__global__ __launch_bounds__(512) void k_gru_scan_fused(
    const float* __restrict__ gi0, const uint4* __restrict__ wl0,
    const float* __restrict__ bhh0, float* __restrict__ hst0,
    float* __restrict__ h1c,
    const float* __restrict__ gi1, const uint4* __restrict__ wl1,
    const float* __restrict__ bhh1, float* __restrict__ hst1,
    int Tc, int do0, int do1, int init0, int init1)
{
    __shared__ __align__(16) uint4    lds_w[8192];        // 128 KB
    __shared__ __align__(16) _Float16 lds_h[2][16][264];  // 16.5 KB

    const int blk = blockIdx.x;
    if (blk < 16) {
        if (!do0) return;
        const int b0 = blk * 16;
        gru_scan_core(gi0 + (size_t)b0 * Tc * G3_, wl0, bhh0,
                      hst0 + (size_t)b0 * H_, h1c + (size_t)b0 * Tc * H_,
                      Tc, init0, lds_w, lds_h);
    } else {
        if (!do1) return;
        const int b0 = (blk - 16) * 16;
        gru_scan_core(gi1 + (size_t)b0 * Tc * G3_, wl1, bhh1,
                      hst1 + (size_t)b0 * H_, nullptr,
                      Tc, init1, lds_w, lds_h);
    }
}

// ---------------------------------------------------------------------------
__global__ void k_fc(const float* __restrict__ h, const float* __restrict__ Wfc,
                     const float* __restrict__ bfc, float* __restrict__ out)
{
    int idx = blockIdx.x * blockDim.x + threadIdx.x;
    if (idx >= B_ * C_) return;
    int b = idx / C_, c = idx % C_;
    const float* hp = h + (size_t)b * H_;
    const float* wp = Wfc + (size_t)c * H_;
    float s = bfc[c];
#pragma unroll 4
    for (int k = 0; k < H_; k++) s = fmaf(hp[k], wp[k], s);
    out[idx] = s;
}

// ---------------------------------------------------------------------------
extern "C" void kernel_launch(void* const* d_in, const int* in_sizes, int n_in,
                              void* d_out, int out_size, void* d_ws, size_t ws_size,
                              hipStream_t stream)
{
    const float* x    = (const float*)d_in[0];
    const float* Wih0 = (const float*)d_in[1];
    const float* Whh0 = (const float*)d_in[2];
    const float* bih0 = (const float*)d_in[3];
    const float* bhh0 = (const float*)d_in[4];
    const float* Wih1 = (const float*)d_in[5];
    const float* Whh1 = (const float*)d_in[6];
    const float* bih1 = (const float*)d_in[7];
    const float* bhh1 = (const float*)d_in[8];
    const float* Wfc  = (const float*)d_in[9];
    const float* bfc  = (const float*)d_in[10];
    float* out = (float*)d_out;

    const size_t wlBytes = (size_t)48 * 512 * sizeof(uint4);   // 393,216 B

    // ---- largest power-of-two T-chunk that fits ws_size -------------------
    const size_t fixedB = 2 * wlBytes + 2 * (size_t)B_ * H_ * 4 + 8192;
    int Tc = 128, tcShift = 7;
    while (Tc > 1) {
        size_t need = fixedB
                    + 2 * (size_t)B_ * Tc * G3_ * 4    // gi0, gi1 chunks
                    + (size_t)B_ * Tc * H_ * 4;        // h1 chunk
        if (need <= ws_size) break;
        Tc >>= 1; tcShift--;
    }
    const int nChunks = T_ / Tc;

    char* ws = (char*)d_ws;
    size_t off = 0;
    auto alloc = [&](size_t bytes) { char* p = ws + off; off += (bytes + 255) & ~(size_t)255; return p; };
    float* gi0  = (float*)alloc((size_t)B_ * Tc * G3_ * 4);
    float* gi1  = (float*)alloc((size_t)B_ * Tc * G3_ * 4);
    float* h1c  = (float*)alloc((size_t)B_ * Tc * H_ * 4);
    uint4* wl0  = (uint4*)alloc(wlBytes);
    uint4* wl1  = (uint4*)alloc(wlBytes);
    float* hst0 = (float*)alloc((size_t)B_ * H_ * 4);
    float* hst1 = (float*)alloc((size_t)B_ * H_ * 4);

    k_pack_whh<<<48, 512, 0, stream>>>(Whh0, wl0);
    k_pack_whh<<<48, 512, 0, stream>>>(Whh1, wl1);

    const dim3 ggrid(G3_ / 64, (B_ * Tc) / 128);

    // software pipeline: fused launch c runs scan0(c) and scan1(c-1)
    k_gemm_nt_bias<<<ggrid, 256, 0, stream>>>(
        x, (long)T_ * D_, Wih0, bih0, gi0, G3_, D_, tcShift);
    k_gru_scan_fused<<<32, 512, 0, stream>>>(
        gi0, wl0, bhh0, hst0, h1c, gi1, wl1, bhh1, hst1,
        Tc, 1, 0, 1, 0);

    for (int c = 1; c < nChunks; ++c) {
        k_gemm_nt_bias<<<ggrid, 256, 0, stream>>>(
            h1c, (long)Tc * H_, Wih1, bih1, gi1, G3_, H_, tcShift);  // chunk c-1
        k_gemm_nt_bias<<<ggrid, 256, 0, stream>>>(
            x + (size_t)c * Tc * D_, (long)T_ * D_, Wih0, bih0, gi0,
            G3_, D_, tcShift);                                        // chunk c
        k_gru_scan_fused<<<32, 512, 0, stream>>>(
            gi0, wl0, bhh0, hst0, h1c, gi1, wl1, bhh1, hst1,
            Tc, 1, 1, 0, c == 1);
    }

    k_gemm_nt_bias<<<ggrid, 256, 0, stream>>>(
        h1c, (long)Tc * H_, Wih1, bih1, gi1, G3_, H_, tcShift);      // last chunk
    k_gru_scan_fused<<<32, 512, 0, stream>>>(
        gi0, wl0, bhh0, hst0, h1c, gi1, wl1, bhh1, hst1,
        Tc, 0, 1, 0, nChunks == 1);

    k_fc<<<10, 256, 0, stream>>>(hst1, Wfc, bfc, out);
}

// Round 4
// 2407.393 us; speedup vs baseline: 2.4634x; 2.4634x over previous
//
#include <hip/hip_runtime.h>
#include <hip/hip_fp16.h>
#include <cstddef>
#include <cstdint>

#define B_  256
#define T_  512
#define D_  128
#define H_  256
#define G3_ 768
#define C_  10

typedef _Float16 f16x8 __attribute__((ext_vector_type(8)));
typedef float    f32x4 __attribute__((ext_vector_type(4)));

__device__ __forceinline__ float sigmoid_f(float x) {
    return 1.0f / (1.0f + __expf(-x));
}
__device__ __forceinline__ float tanh_f(float x) {
    return 1.0f - 2.0f / (__expf(2.0f * x) + 1.0f);
}

__device__ __forceinline__ unsigned int packh2(float a, float b) {
    unsigned short lo = __half_as_ushort(__float2half(a));   // k even -> lo16
    unsigned short hi = __half_as_ushort(__float2half(b));   // k odd  -> hi16
    return (unsigned int)lo | ((unsigned int)hi << 16);
}

// ---------------------------------------------------------------------------
// Pack Whh[3H][H] fp32 -> f16 MFMA B-fragment stream for the scan.
// (unchanged, harness-verified layout)
// ---------------------------------------------------------------------------
__global__ void k_pack_whh(const float* __restrict__ Whh, uint4* __restrict__ Wl) {
    const int wnt = blockIdx.x;          // w*6 + nt
    const int w  = wnt / 6;
    const int nt = wnt % 6;
    const int t  = threadIdx.x;
    const int kt = t >> 6;
    const int l  = t & 63;
    const int g  = nt >> 1;
    const int n  = g * 256 + w * 32 + (nt & 1) * 16 + (l & 15);
    const int k0 = kt * 32 + (l >> 4) * 8;
    const float* row = Whh + (size_t)n * H_ + k0;
    uint4 u;
    u.x = packh2(row[0], row[1]);
    u.y = packh2(row[2], row[3]);
    u.z = packh2(row[4], row[5]);
    u.w = packh2(row[6], row[7]);
    Wl[(size_t)wnt * 512 + t] = u;
}

// ---------------------------------------------------------------------------
// Pack Wih[768][K] fp32 -> f16 B-fragments for the gi GEMM.
// Frag f = ntile*KT + kt (ntile 0..47, kt 0..KT-1, KT=K/32):
//   lane l supplies B[k][n]: n = ntile*16 + (l&15), k = kt*32 + (l>>4)*8 + i.
// Same lane->element mapping as k_pack_whh (harness-verified by the scan).
// ---------------------------------------------------------------------------
__global__ void k_pack_wih(const float* __restrict__ W, uint4* __restrict__ Wp,
                           int K) {
    const int KT = K >> 5;
    const int f  = blockIdx.x * 4 + (threadIdx.x >> 6);
    const int l  = threadIdx.x & 63;
    const int ntile = f / KT;
    const int kt    = f - ntile * KT;
    const int n  = ntile * 16 + (l & 15);
    const int k0 = kt * 32 + (l >> 4) * 8;
    const float* row = W + (size_t)n * K + k0;
    uint4 u;
    u.x = packh2(row[0], row[1]);
    u.y = packh2(row[2], row[3]);
    u.z = packh2(row[4], row[5]);
    u.w = packh2(row[6], row[7]);
    Wp[(size_t)f * 64 + l] = u;
}

// ---------------------------------------------------------------------------
// gi GEMM on the MATRIX pipe: C[M,768] = A[M,K](f32->f16) @ W^T(f16) + bias,
// f32 accumulate. A rows are chunk-major (tcShift mapping, as before); C row
// index == global chunk-major row id (b*Tc + t), layout identical to the old
// fp32 GEMM so the scan's gi reader is untouched.
// Block 256 thr = 4 waves; tile 128x64; wave w owns rows [w*32, w*32+32)
// (2 row-tiles) x 4 col-tiles. Per kt (K-step 32): 2 A-frag loads
// (2x dwordx4 f32 + cvt) + 4 W-frag loads (dwordx4 f16) + 8 MFMA.
// No LDS, no barriers. ~64 MFMA/wave @ K=256.
// ---------------------------------------------------------------------------
__global__ __launch_bounds__(256) void k_gemm_f16(
    const float* __restrict__ A, long Abstride, int tcShift,
    const uint4* __restrict__ Wp,
    const float* __restrict__ bias, float* __restrict__ C,
    int K)
{
    const int tid = threadIdx.x;
    const int w  = tid >> 6;
    const int l  = tid & 63;
    const int c  = l & 15;
    const int g4 = l >> 4;
    const int m0 = blockIdx.y * 128;
    const int n0 = blockIdx.x * 64;
    const int KT = K >> 5;
    const int mask = (1 << tcShift) - 1;

    const float* Arow0;
    const float* Arow1;
    {
        int mg0 = m0 + w * 32 + c;
        int mg1 = mg0 + 16;
        Arow0 = A + (size_t)(mg0 >> tcShift) * Abstride + (size_t)(mg0 & mask) * K + g4 * 8;
        Arow1 = A + (size_t)(mg1 >> tcShift) * Abstride + (size_t)(mg1 & mask) * K + g4 * 8;
    }
    const uint4* Wb = Wp + (size_t)((n0 >> 4) * KT) * 64 + l;

    f32x4 acc[2][4] = {};

    for (int kt = 0; kt < KT; kt++) {
        f16x8 a0, a1;
        {
            float4 lo = *(const float4*)(Arow0 + kt * 32);
            float4 hi = *(const float4*)(Arow0 + kt * 32 + 4);
            a0[0] = (_Float16)lo.x; a0[1] = (_Float16)lo.y;
            a0[2] = (_Float16)lo.z; a0[3] = (_Float16)lo.w;
            a0[4] = (_Float16)hi.x; a0[5] = (_Float16)hi.y;
            a0[6] = (_Float16)hi.z; a0[7] = (_Float16)hi.w;
        }
        {
            float4 lo = *(const float4*)(Arow1 + kt * 32);
            float4 hi = *(const float4*)(Arow1 + kt * 32 + 4);
            a1[0] = (_Float16)lo.x; a1[1] = (_Float16)lo.y;
            a1[2] = (_Float16)lo.z; a1[3] = (_Float16)lo.w;
            a1[4] = (_Float16)hi.x; a1[5] = (_Float16)hi.y;
            a1[6] = (_Float16)hi.z; a1[7] = (_Float16)hi.w;
        }
#pragma unroll
        for (int ct = 0; ct < 4; ct++) {
            uint4 wf = Wb[(size_t)(ct * KT + kt) * 64];
            acc[0][ct] = __builtin_amdgcn_mfma_f32_16x16x32_f16(
                a0, __builtin_bit_cast(f16x8, wf), acc[0][ct], 0, 0, 0);
            acc[1][ct] = __builtin_amdgcn_mfma_f32_16x16x32_f16(
                a1, __builtin_bit_cast(f16x8, wf), acc[1][ct], 0, 0, 0);
        }
    }

    // D layout: row = tile_row0 + g4*4 + reg, col = tile_col0 + c (verified).
#pragma unroll
    for (int ct = 0; ct < 4; ct++) {
        const int n = n0 + ct * 16 + c;
        const float bv = bias[n];
#pragma unroll
        for (int rt = 0; rt < 2; rt++) {
#pragma unroll
            for (int rg = 0; rg < 4; rg++) {
                const int m = m0 + w * 32 + rt * 16 + g4 * 4 + rg;
                C[(size_t)m * G3_ + n] = acc[rt][ct][rg] + bv;
            }
        }
    }
}

// ---------------------------------------------------------------------------
// MFMA scan -- EXACT R1 structure (370 us measured; VGPR 124).
// R2 ("+v" value launder) and R3 ("+a" AGPR pin) both regressed; the
// allocator's remat-from-L2 of the 32 weight frags per step is the cheapest
// observed weight path for this structure. Do not re-litigate without disasm.
// ---------------------------------------------------------------------------
__device__ __forceinline__ void gru_scan_core(
    const float* __restrict__ gi,      // + b0*Tc*G3   [16 rows][Tc][3H]
    const uint4* __restrict__ Wpk,     // [48*8][64] packed B-fragments
    const float* __restrict__ bhh,
    float* __restrict__ h_state,       // + b0*H
    float* __restrict__ out_seq,       // + b0*Tc*H or nullptr
    int Tc, int initZero,
    uint4 (&lds_w)[8192], _Float16 (&lds_h)[2][16][264])
{
    const int tid = threadIdx.x;
    const int w  = tid >> 6;       // wave 0..7
    const int l  = tid & 63;
    const int c  = l & 15;
    const int g4 = l >> 4;         // 0..3

    // ---- stage LDS-resident weight frags (nt 4,5 of every wave) -----------
#pragma unroll
    for (int i = 0; i < 16; i++) {
        int idx = i * 512 + tid;                       // (wv*16 + fl)*64 + ln
        lds_w[idx] = Wpk[(size_t)(idx >> 10) * 3072 + 2048 + (idx & 1023)];
    }

    // ---- register-resident frags: nt 0..3 x kt 0..7 -----------------------
    uint4 wreg[32];
#pragma unroll
    for (int nt = 0; nt < 4; nt++)
#pragma unroll
        for (int kt = 0; kt < 8; kt++)
            wreg[nt * 8 + kt] = Wpk[(size_t)((w * 6 + nt) * 8 + kt) * 64 + l];

    // ---- lane ownership: m = g4*4+r, j = w*32 + jj*16 + c -----------------
    const int jA = w * 32 + c;
    const float br0 = bhh[jA],       br1 = bhh[jA + 16];
    const float bz0 = bhh[256 + jA], bz1 = bhh[256 + jA + 16];
    const float bn0 = bhh[512 + jA], bn1 = bhh[512 + jA + 16];

    float hreg[4][2];
#pragma unroll
    for (int r = 0; r < 4; r++) {
        const int m = g4 * 4 + r;
        if (initZero) {
            hreg[r][0] = 0.0f;
            hreg[r][1] = 0.0f;
        } else {
            hreg[r][0] = h_state[(size_t)m * H_ + jA];
            hreg[r][1] = h_state[(size_t)m * H_ + jA + 16];
        }
        lds_h[0][m][jA]      = (_Float16)hreg[r][0];
        lds_h[0][m][jA + 16] = (_Float16)hreg[r][1];
    }
    __syncthreads();

    int cur = 0;
    for (int tt = 0; tt < Tc; ++tt) {
        // LICM barrier: opaque LDS offset each step.
        unsigned wb = (unsigned)(w * 1024 + l);
        asm volatile("" : "+v"(wb));

        // gi prefetch: issued now, consumed after the MFMA block.
        float gic[4][6];
#pragma unroll
        for (int r = 0; r < 4; r++) {
            const float* gp = gi + ((size_t)(g4 * 4 + r) * Tc + tt) * G3_ + jA;
#pragma unroll
            for (int gg = 0; gg < 3; gg++) {
                gic[r][gg * 2 + 0] = gp[gg * 256];
                gic[r][gg * 2 + 1] = gp[gg * 256 + 16];
            }
        }

        f32x4 acc[6] = {};
#pragma unroll
        for (int kt = 0; kt < 8; kt++) {
            // A-frag: lane supplies h[c][kt*32 + g4*8 .. +8]  (ds_read_b128)
            f16x8 a = *(const f16x8*)&lds_h[cur][c][kt * 32 + g4 * 8];
#pragma unroll
            for (int nt = 0; nt < 4; nt++)
                acc[nt] = __builtin_amdgcn_mfma_f32_16x16x32_f16(
                    a, __builtin_bit_cast(f16x8, wreg[nt * 8 + kt]), acc[nt], 0, 0, 0);
            uint4 u4 = lds_w[wb + kt * 64];            // nt=4 frag
            acc[4] = __builtin_amdgcn_mfma_f32_16x16x32_f16(
                a, __builtin_bit_cast(f16x8, u4), acc[4], 0, 0, 0);
            uint4 u5 = lds_w[wb + (8 + kt) * 64];      // nt=5 frag
            acc[5] = __builtin_amdgcn_mfma_f32_16x16x32_f16(
                a, __builtin_bit_cast(f16x8, u5), acc[5], 0, 0, 0);
        }

        // D layout: row m = g4*4 + reg, col = tile_c0 + c.
        // nt 0/1 = r-gate (jj=0/1), nt 2/3 = z, nt 4/5 = n.
#pragma unroll
        for (int r = 0; r < 4; r++) {
            const int m = g4 * 4 + r;
#pragma unroll
            for (int jj = 0; jj < 2; jj++) {
                float rg = sigmoid_f(gic[r][jj]     + acc[jj][r]     + (jj ? br1 : br0));
                float zg = sigmoid_f(gic[r][2 + jj] + acc[2 + jj][r] + (jj ? bz1 : bz0));
                float ng = tanh_f(gic[r][4 + jj] +
                                  rg * (acc[4 + jj][r] + (jj ? bn1 : bn0)));
                float hn = (1.0f - zg) * ng + zg * hreg[r][jj];
                hreg[r][jj] = hn;
                lds_h[cur ^ 1][m][jA + jj * 16] = (_Float16)hn;
                if (out_seq)
                    out_seq[((size_t)m * Tc + tt) * H_ + jA + jj * 16] = hn;
            }
        }
        if (tt == Tc - 1) {
#pragma unroll
            for (int r = 0; r < 4; r++) {
                const int m = g4 * 4 + r;
                h_state[(size_t)m * H_ + jA]      = hreg[r][0];
                h_state[(size_t)m * H_ + jA + 16] = hreg[r][1];
            }
        }
        __syncthreads();
        cur ^= 1;
    }
}

// Fused layer-pipelined scan: blocks 0..15 -> layer0 chunk c (16 rows each),
// blocks 16..31 -> layer1 chunk c-1. 148 KB LDS -> 1 block/CU naturally.
__global__ __launch_bounds__(512, 2) void k_gru_scan_fused(
    const float* __restrict__ gi0, const uint4* __restrict__ wl0,
    const float* __restrict__ bhh0, float* __restrict__ hst0,
    float* __restrict__ h1c,
    const float* __restrict__ gi1, const uint4* __restrict__ wl1,
    const float* __restrict__ bhh1, float* __restrict__ hst1,
    int Tc, int do0, int do1, int init0, int init1)
{
    __shared__ __align__(16) uint4    lds_w[8192];        // 128 KB
    __shared__ __align__(16) _Float16 lds_h[2][16][264];  // 16.5 KB

    const int blk = blockIdx.x;
    if (blk < 16) {
        if (!do0) return;
        const int b0 = blk * 16;
        gru_scan_core(gi0 + (size_t)b0 * Tc * G3_, wl0, bhh0,
                      hst0 + (size_t)b0 * H_, h1c + (size_t)b0 * Tc * H_,
                      Tc, init0, lds_w, lds_h);
    } else {
        if (!do1) return;
        const int b0 = (blk - 16) * 16;
        gru_scan_core(gi1 + (size_t)b0 * Tc * G3_, wl1, bhh1,
                      hst1 + (size_t)b0 * H_, nullptr,
                      Tc, init1, lds_w, lds_h);
    }
}

// ---------------------------------------------------------------------------
__global__ void k_fc(const float* __restrict__ h, const float* __restrict__ Wfc,
                     const float* __restrict__ bfc, float* __restrict__ out)
{
    int idx = blockIdx.x * blockDim.x + threadIdx.x;
    if (idx >= B_ * C_) return;
    int b = idx / C_, c = idx % C_;
    const float* hp = h + (size_t)b * H_;
    const float* wp = Wfc + (size_t)c * H_;
    float s = bfc[c];
#pragma unroll 4
    for (int k = 0; k < H_; k++) s = fmaf(hp[k], wp[k], s);
    out[idx] = s;
}

// ---------------------------------------------------------------------------
extern "C" void kernel_launch(void* const* d_in, const int* in_sizes, int n_in,
                              void* d_out, int out_size, void* d_ws, size_t ws_size,
                              hipStream_t stream)
{
    const float* x    = (const float*)d_in[0];
    const float* Wih0 = (const float*)d_in[1];
    const float* Whh0 = (const float*)d_in[2];
    const float* bih0 = (const float*)d_in[3];
    const float* bhh0 = (const float*)d_in[4];
    const float* Wih1 = (const float*)d_in[5];
    const float* Whh1 = (const float*)d_in[6];
    const float* bih1 = (const float*)d_in[7];
    const float* bhh1 = (const float*)d_in[8];
    const float* Wfc  = (const float*)d_in[9];
    const float* bfc  = (const float*)d_in[10];
    float* out = (float*)d_out;

    const size_t wlBytes  = (size_t)48 * 512 * sizeof(uint4);   // 393,216 B
    const size_t wp0Bytes = (size_t)48 * 4 * 64 * sizeof(uint4); // 196,608 B
    const size_t wp1Bytes = (size_t)48 * 8 * 64 * sizeof(uint4); // 393,216 B

    // ---- largest power-of-two T-chunk that fits ws_size -------------------
    const size_t fixedB = 2 * wlBytes + wp0Bytes + wp1Bytes
                        + 2 * (size_t)B_ * H_ * 4 + 16384;
    int Tc = 128, tcShift = 7;
    while (Tc > 1) {
        size_t need = fixedB
                    + 2 * (size_t)B_ * Tc * G3_ * 4    // gi0, gi1 chunks
                    + (size_t)B_ * Tc * H_ * 4;        // h1 chunk
        if (need <= ws_size) break;
        Tc >>= 1; tcShift--;
    }
    const int nChunks = T_ / Tc;

    char* ws = (char*)d_ws;
    size_t off = 0;
    auto alloc = [&](size_t bytes) { char* p = ws + off; off += (bytes + 255) & ~(size_t)255; return p; };
    float* gi0  = (float*)alloc((size_t)B_ * Tc * G3_ * 4);
    float* gi1  = (float*)alloc((size_t)B_ * Tc * G3_ * 4);
    float* h1c  = (float*)alloc((size_t)B_ * Tc * H_ * 4);
    uint4* wl0  = (uint4*)alloc(wlBytes);
    uint4* wl1  = (uint4*)alloc(wlBytes);
    uint4* wp0  = (uint4*)alloc(wp0Bytes);
    uint4* wp1  = (uint4*)alloc(wp1Bytes);
    float* hst0 = (float*)alloc((size_t)B_ * H_ * 4);
    float* hst1 = (float*)alloc((size_t)B_ * H_ * 4);

    k_pack_whh<<<48, 512, 0, stream>>>(Whh0, wl0);
    k_pack_whh<<<48, 512, 0, stream>>>(Whh1, wl1);
    k_pack_wih<<<48, 256, 0, stream>>>(Wih0, wp0, D_);   // KT=4 -> 192 frags
    k_pack_wih<<<96, 256, 0, stream>>>(Wih1, wp1, H_);   // KT=8 -> 384 frags

    const dim3 ggrid(G3_ / 64, (B_ * Tc) / 128);

    // software pipeline: fused launch c runs scan0(c) and scan1(c-1)
    k_gemm_f16<<<ggrid, 256, 0, stream>>>(
        x, (long)T_ * D_, tcShift, wp0, bih0, gi0, D_);
    k_gru_scan_fused<<<32, 512, 0, stream>>>(
        gi0, wl0, bhh0, hst0, h1c, gi1, wl1, bhh1, hst1,
        Tc, 1, 0, 1, 0);

    for (int c = 1; c < nChunks; ++c) {
        k_gemm_f16<<<ggrid, 256, 0, stream>>>(
            h1c, (long)Tc * H_, tcShift, wp1, bih1, gi1, H_);        // chunk c-1
        k_gemm_f16<<<ggrid, 256, 0, stream>>>(
            x + (size_t)c * Tc * D_, (long)T_ * D_, tcShift, wp0, bih0, gi0, D_);
        k_gru_scan_fused<<<32, 512, 0, stream>>>(
            gi0, wl0, bhh0, hst0, h1c, gi1, wl1, bhh1, hst1,
            Tc, 1, 1, 0, c == 1);
    }

    k_gemm_f16<<<ggrid, 256, 0, stream>>>(
        h1c, (long)Tc * H_, tcShift, wp1, bih1, gi1, H_);            // last chunk
    k_gru_scan_fused<<<32, 512, 0, stream>>>(
        gi0, wl0, bhh0, hst0, h1c, gi1, wl1, bhh1, hst1,
        Tc, 0, 1, 0, nChunks == 1);

    k_fc<<<10, 256, 0, stream>>>(hst1, Wfc, bfc, out);
}